// Round 1
// 255.627 us; speedup vs baseline: 1.1709x; 1.1709x over previous
//
#include <hip/hip_runtime.h>

typedef __attribute__((ext_vector_type(8))) short short8;
typedef __attribute__((ext_vector_type(4))) float f32x4;

#define MFMA16(a, b, c) __builtin_amdgcn_mfma_f32_16x16x32_bf16(a, b, c, 0, 0, 0)

// Problem constants
#define BATCH 2
#define SEQ 2048
#define DMODEL 1024
#define NHEADS 16
#define HDIM 64
#define MROWS (BATCH * SEQ)      // 4096
#define N_QKV (3 * DMODEL)       // 3072

// softmax scale 1/sqrt(64) folded with log2(e) into Q at projection time,
// so attention logits are already in the exp2 domain.
#define QSCALE 0.1803368801111184f

// global->LDS direct DMA, 16B/lane, dest = wave-uniform base + lane*16 (m97/m104)
#define GLDS16(gp, lp)                                                       \
  __builtin_amdgcn_global_load_lds(                                          \
      (const __attribute__((address_space(1))) void*)(gp),                   \
      (__attribute__((address_space(3))) void*)(lp), 16, 0, 0)

static __device__ __forceinline__ unsigned short f2bf(float f) {
  unsigned int u = __float_as_uint(f);
  u = (u + 0x7fff + ((u >> 16) & 1)) >> 16;   // round-to-nearest-even
  return (unsigned short)u;
}

static __device__ __forceinline__ unsigned int pk2bf(float lo, float hi) {
  unsigned int r;
  asm("v_cvt_pk_bf16_f32 %0, %1, %2" : "=v"(r) : "v"(lo), "v"(hi));
  return r;
}

// ---------------------------------------------------------------- cvt fp32->bf16
__global__ void cvt_kernel(const float* __restrict__ in,
                           unsigned short* __restrict__ out, int n4) {
  int i = blockIdx.x * blockDim.x + threadIdx.x;
  if (i >= n4) return;
  f32x4 v = ((const f32x4*)in)[i];
  ushort4 o;
  o.x = f2bf(v[0]); o.y = f2bf(v[1]); o.z = f2bf(v[2]); o.w = f2bf(v[3]);
  ((ushort4*)out)[i] = o;
}

// ---------------------------------------------------------------- mask -> bitmask
__global__ void mask_to_bits(const int* __restrict__ mask,
                             unsigned int* __restrict__ bits) {
  int i = blockIdx.x * blockDim.x + threadIdx.x;   // 0 .. 2048*64-1
  const int* p = mask + (size_t)i * 32;
  unsigned int v = 0;
#pragma unroll
  for (int b = 0; b < 32; ++b) v |= (p[b] != 0 ? 1u : 0u) << b;
  bits[i] = v;
}

// ---------------------------------------------------------------- NT GEMM, 128x128 tile
// C[M,N] = A[M,K] * B[N,K]^T + bias[N]
template <int EPI>
__global__ __launch_bounds__(256) void gemm_bt(
    const unsigned short* __restrict__ A, const unsigned short* __restrict__ Bm,
    const float* __restrict__ bias, int Kdim, int Ndim,
    unsigned short* __restrict__ qb, unsigned short* __restrict__ kb,
    unsigned short* __restrict__ vtb, float* __restrict__ Cout) {
  __shared__ __align__(16) unsigned short lA[128 * 40];
  __shared__ __align__(16) unsigned short lB[128 * 40];

  int t = threadIdx.x;
  int m0 = blockIdx.y * 128, n0 = blockIdx.x * 128;
  int w = t >> 6, lane = t & 63, quad = lane >> 4, l16 = lane & 15;
  int wm = (w >> 1) * 64, wn = (w & 1) * 64;

  f32x4 acc[4][4];
#pragma unroll
  for (int i = 0; i < 4; ++i)
#pragma unroll
    for (int j = 0; j < 4; ++j) acc[i][j] = (f32x4){0.f, 0.f, 0.f, 0.f};

  int nK = Kdim >> 5;
  for (int kk = 0; kk < nK; ++kk) {
    __syncthreads();
#pragma unroll
    for (int c = 0; c < 2; ++c) {
      int id = t + c * 256;
      int row = id >> 2, c8 = (id & 3) << 3;
      *(uint4*)&lA[row * 40 + c8] =
          *(const uint4*)&A[(size_t)(m0 + row) * Kdim + (kk << 5) + c8];
      *(uint4*)&lB[row * 40 + c8] =
          *(const uint4*)&Bm[(size_t)(n0 + row) * Kdim + (kk << 5) + c8];
    }
    __syncthreads();
    short8 af[4], bfr[4];
#pragma unroll
    for (int i = 0; i < 4; ++i)
      af[i] = *(const short8*)&lA[(wm + i * 16 + l16) * 40 + quad * 8];
#pragma unroll
    for (int j = 0; j < 4; ++j)
      bfr[j] = *(const short8*)&lB[(wn + j * 16 + l16) * 40 + quad * 8];
#pragma unroll
    for (int i = 0; i < 4; ++i)
#pragma unroll
      for (int j = 0; j < 4; ++j) acc[i][j] = MFMA16(af[i], bfr[j], acc[i][j]);
  }

#pragma unroll
  for (int j = 0; j < 4; ++j) {
    int n = n0 + wn + j * 16 + l16;
    float bs = bias[n];
#pragma unroll
    for (int i = 0; i < 4; ++i) {
#pragma unroll
      for (int r = 0; r < 4; ++r) {
        int m = m0 + wm + i * 16 + quad * 4 + r;
        float v = acc[i][j][r] + bs;
        if (EPI == 0) {
          int b = m >> 11, s = m & 2047;
          int h = n / 192, rr = n % 192;
          int bh = (b << 4) + h;
          if (rr < 64)
            qb[((size_t)bh * SEQ + s) * HDIM + rr] = f2bf(v * QSCALE);
          else if (rr < 128)
            kb[((size_t)bh * SEQ + s) * HDIM + (rr - 64)] = f2bf(v);
          else
            vtb[((size_t)bh * HDIM + (rr - 128)) * SEQ + s] = f2bf(v);
        } else {
          Cout[(size_t)m * Ndim + n] = v;
        }
      }
    }
  }
}

// ---------------------------------------------------------------- flash attention
// grid: (16 q-tiles of 128 rows, 32 bh). block 512 = 8 waves; wave owns 16 q-rows.
// Swapped-operand scheme: S^T = mfma(K, Q) and O^T = mfma(V^T, P), so the
// per-q-row softmax state (m, l, alpha, 1/l) lives entirely at lane l16 —
// reductions are 15 in-lane ops + 2 shfl_xor (quads), no other cross-lane.
// K/V tiles [64 keys/d][64] staged unpadded via global_load_lds with
// XOR-swizzled source (byte ^= (row&7)<<4), double-buffered, 1 barrier/tile.
__global__ __launch_bounds__(512, 4) void attn_kernel(
    const unsigned short* __restrict__ qbuf, const unsigned short* __restrict__ kbuf,
    const unsigned short* __restrict__ vtbuf, const unsigned int* __restrict__ mbits,
    unsigned short* __restrict__ ctx) {
  __shared__ __align__(16) unsigned short lK[2][64 * 64];
  __shared__ __align__(16) unsigned short lV[2][64 * 64];   // V^T: [d][key]
  __shared__ __align__(16) unsigned short lP[128 * 64];     // [q][key], per-wave rows

  int qt = blockIdx.x, bh = blockIdx.y;
  int q0 = qt * 128;
  const unsigned short* Q = qbuf + (size_t)bh * SEQ * HDIM;
  const unsigned short* K = kbuf + (size_t)bh * SEQ * HDIM;
  const unsigned short* VT = vtbuf + (size_t)bh * HDIM * SEQ;

  int t = threadIdx.x;
  int w = t >> 6, lane = t & 63, quad = lane >> 4, l16 = lane & 15;
  int swz = (l16 & 7) << 4;          // byte-XOR swizzle for rows this lane reads

  // Q fragments in registers (scale*log2e pre-folded at projection)
  int qrow = q0 + w * 16 + l16;      // 0..2047
  short8 qf0 = *(const short8*)&Q[(size_t)qrow * HDIM + quad * 8];
  short8 qf1 = *(const short8*)&Q[(size_t)qrow * HDIM + 32 + quad * 8];

  f32x4 o[4];
#pragma unroll
  for (int jt = 0; jt < 4; ++jt) o[jt] = (f32x4){0.f, 0.f, 0.f, 0.f};
  float mi = -INFINITY, li = 0.f;

  // staging: wave w fills LDS rows w*8..w*8+7; lane covers 16B slot (lane&7).
  // source col pre-swizzled so linear LDS dest ends up XOR-swizzled (m173).
  int srow = w * 8 + (lane >> 3);
  int scol = ((lane & 7) ^ (srow & 7)) << 3;   // shorts
  const unsigned short* gK = K + (size_t)srow * HDIM + scol;
  const unsigned short* gV = VT + (size_t)srow * SEQ + scol;

  GLDS16(gK, &lK[0][w * 512]);
  GLDS16(gV, &lV[0][w * 512]);
  gK += 64 * HDIM;
  gV += 64;

  const unsigned int* mrow = mbits + (size_t)qrow * 64;
  unsigned short* lPr = &lP[(w * 16 + l16) * 64];

  for (int it = 0; it < SEQ / 64; ++it) {
    __syncthreads();   // drains vmcnt -> tile `it` staged; prev reads done
    if (it + 1 < SEQ / 64) {         // prefetch next tile into other half
      GLDS16(gK, &lK[(it + 1) & 1][w * 512]);
      GLDS16(gV, &lV[(it + 1) & 1][w * 512]);
      gK += 64 * HDIM;
      gV += 64;
    }
    const unsigned short* cK = lK[it & 1];
    const unsigned short* cV = lV[it & 1];

    // S^T: s[j][r] = logit[key = it*64 + j*16 + quad*4 + r][qrow] (log2 domain)
    f32x4 s[4];
#pragma unroll
    for (int j = 0; j < 4; ++j) {
      const char* kr = (const char*)&cK[(j * 16 + l16) * 64];
      short8 ka = *(const short8*)(kr + ((quad * 16) ^ swz));
      short8 kc = *(const short8*)(kr + ((64 + quad * 16) ^ swz));
      f32x4 z = (f32x4){0.f, 0.f, 0.f, 0.f};
      z = MFMA16(ka, qf0, z);
      z = MFMA16(kc, qf1, z);
      s[j] = z;
    }

    // mask: one 8B load per lane per tile (bit = key within 64-key tile)
    uint2 mw = *(const uint2*)&mrow[it * 2];
    unsigned int ma = mw.x >> (quad * 4);
    unsigned int mb = mw.y >> (quad * 4);
#pragma unroll
    for (int j = 0; j < 4; ++j) {
      unsigned int sel = (j < 2) ? ma : mb;
      int sh = (j & 1) << 4;
#pragma unroll
      for (int r = 0; r < 4; ++r)
        s[j][r] = (sel & (1u << (sh + r))) ? s[j][r] : -1e30f;
    }

    // online softmax; full q-row = 16 in-lane values x 4 quads (xor 16/32)
    float mx = fmaxf(fmaxf(s[0][0], s[0][1]), fmaxf(s[0][2], s[0][3]));
#pragma unroll
    for (int j = 1; j < 4; ++j)
      mx = fmaxf(mx, fmaxf(fmaxf(s[j][0], s[j][1]), fmaxf(s[j][2], s[j][3])));
    mx = fmaxf(mx, __shfl_xor(mx, 16));
    mx = fmaxf(mx, __shfl_xor(mx, 32));
    float mn = fmaxf(mi, mx);
    float al = exp2f(mi - mn);
    float rs = 0.f;
#pragma unroll
    for (int j = 0; j < 4; ++j)
#pragma unroll
      for (int r = 0; r < 4; ++r) {
        float p = exp2f(s[j][r] - mn);
        s[j][r] = p;
        rs += p;
      }
    rs += __shfl_xor(rs, 16);
    rs += __shfl_xor(rs, 32);
    li = li * al + rs;
    mi = mn;
#pragma unroll
    for (int jt = 0; jt < 4; ++jt)
#pragma unroll
      for (int r = 0; r < 4; ++r) o[jt][r] *= al;

    // P -> bf16 (cvt_pk) -> LDS; 4 contiguous keys per lane -> ds_write_b64
#pragma unroll
    for (int j = 0; j < 4; ++j) {
      uint2 u;
      u.x = pk2bf(s[j][0], s[j][1]);
      u.y = pk2bf(s[j][2], s[j][3]);
      *(uint2*)((char*)lPr + ((j * 32 + quad * 8) ^ swz)) = u;
    }

    // O^T += V^T P : o[jt][r] = O[d = jt*16 + quad*4 + r][qrow]
#pragma unroll
    for (int kh = 0; kh < 2; ++kh) {
      short8 pf = *(const short8*)((const char*)lPr + ((kh * 64 + quad * 16) ^ swz));
#pragma unroll
      for (int jt = 0; jt < 4; ++jt) {
        const char* vr = (const char*)&cV[(jt * 16 + l16) * 64];
        short8 vf = *(const short8*)(vr + ((kh * 64 + quad * 16) ^ swz));
        o[jt] = MFMA16(vf, pf, o[jt]);
      }
    }
  }

  // epilogue: 1/li is lane-local; d runs over r -> 4 contiguous bf16 per store
  float inv = 1.f / li;
  int b = bh >> 4, h = bh & 15;
  unsigned short* crow = ctx + ((size_t)(b * SEQ + qrow)) * DMODEL + h * HDIM;
#pragma unroll
  for (int jt = 0; jt < 4; ++jt) {
    uint2 u;
    u.x = pk2bf(o[jt][0] * inv, o[jt][1] * inv);
    u.y = pk2bf(o[jt][2] * inv, o[jt][3] * inv);
    *(uint2*)&crow[jt * 16 + quad * 4] = u;
  }
}

// ---------------------------------------------------------------- launch
extern "C" void kernel_launch(void* const* d_in, const int* in_sizes, int n_in,
                              void* d_out, int out_size, void* d_ws, size_t ws_size,
                              hipStream_t stream) {
  const float* x = (const float*)d_in[0];
  const int* mask = (const int*)d_in[1];
  const float* w_qkv = (const float*)d_in[2];
  const float* b_qkv = (const float*)d_in[3];
  const float* w_o = (const float*)d_in[4];
  const float* b_o = (const float*)d_in[5];
  float* out = (float*)d_out;

  char* ws = (char*)d_ws;
  unsigned short* xb = (unsigned short*)(ws);                       // 8 MB
  unsigned short* wqkvb = (unsigned short*)(ws + (8ull << 20));     // 6 MB
  unsigned short* wob = (unsigned short*)(ws + (14ull << 20));      // 2 MB
  unsigned short* qb = (unsigned short*)(ws + (16ull << 20));       // 8 MB
  unsigned short* kb = (unsigned short*)(ws + (24ull << 20));       // 8 MB
  unsigned short* vtb = (unsigned short*)(ws + (32ull << 20));      // 8 MB
  unsigned short* ctx = (unsigned short*)(ws + (40ull << 20));      // 8 MB
  unsigned int* mbits = (unsigned int*)(ws + (48ull << 20));        // 512 KB

  cvt_kernel<<<4096, 256, 0, stream>>>(x, xb, (MROWS * DMODEL) / 4);
  cvt_kernel<<<3072, 256, 0, stream>>>(w_qkv, wqkvb, (N_QKV * DMODEL) / 4);
  cvt_kernel<<<1024, 256, 0, stream>>>(w_o, wob, (DMODEL * DMODEL) / 4);
  mask_to_bits<<<512, 256, 0, stream>>>(mask, mbits);

  gemm_bt<0><<<dim3(N_QKV / 128, MROWS / 128), 256, 0, stream>>>(
      xb, wqkvb, b_qkv, DMODEL, N_QKV, qb, kb, vtb, nullptr);

  attn_kernel<<<dim3(SEQ / 128, BATCH * NHEADS), 512, 0, stream>>>(
      qb, kb, vtb, mbits, ctx);

  gemm_bt<1><<<dim3(DMODEL / 128, MROWS / 128), 256, 0, stream>>>(
      ctx, wob, b_o, DMODEL, DMODEL, nullptr, nullptr, nullptr, out);
}

// Round 2
// 252.918 us; speedup vs baseline: 1.1834x; 1.0107x over previous
//
#include <hip/hip_runtime.h>

typedef __attribute__((ext_vector_type(8))) short short8;
typedef __attribute__((ext_vector_type(4))) float f32x4;

#define MFMA16(a, b, c) __builtin_amdgcn_mfma_f32_16x16x32_bf16(a, b, c, 0, 0, 0)

// Problem constants
#define BATCH 2
#define SEQ 2048
#define DMODEL 1024
#define NHEADS 16
#define HDIM 64
#define MROWS (BATCH * SEQ)      // 4096
#define N_QKV (3 * DMODEL)       // 3072

// softmax scale 1/sqrt(64) folded with log2(e) into Q at projection time,
// so attention logits are already in the exp2 domain.
#define QSCALE 0.1803368801111184f

// global->LDS direct DMA, 16B/lane, dest = wave-uniform base + lane*16 (m97/m104)
#define GLDS16(gp, lp)                                                       \
  __builtin_amdgcn_global_load_lds(                                          \
      (const __attribute__((address_space(1))) void*)(gp),                   \
      (__attribute__((address_space(3))) void*)(lp), 16, 0, 0)

static __device__ __forceinline__ unsigned short f2bf(float f) {
  unsigned int u = __float_as_uint(f);
  u = (u + 0x7fff + ((u >> 16) & 1)) >> 16;   // round-to-nearest-even
  return (unsigned short)u;
}

static __device__ __forceinline__ unsigned int pk2bf(float lo, float hi) {
  unsigned int r;
  asm("v_cvt_pk_bf16_f32 %0, %1, %2" : "=v"(r) : "v"(lo), "v"(hi));
  return r;
}

// ---------------------------------------------------------------- cvt fp32->bf16
__global__ void cvt_kernel(const float* __restrict__ in,
                           unsigned short* __restrict__ out, int n4) {
  int i = blockIdx.x * blockDim.x + threadIdx.x;
  if (i >= n4) return;
  f32x4 v = ((const f32x4*)in)[i];
  ushort4 o;
  o.x = f2bf(v[0]); o.y = f2bf(v[1]); o.z = f2bf(v[2]); o.w = f2bf(v[3]);
  ((ushort4*)out)[i] = o;
}

// ---------------------------------------------------------------- mask -> bitmask
__global__ void mask_to_bits(const int* __restrict__ mask,
                             unsigned int* __restrict__ bits) {
  int i = blockIdx.x * blockDim.x + threadIdx.x;   // 0 .. 2048*64-1
  const int* p = mask + (size_t)i * 32;
  unsigned int v = 0;
#pragma unroll
  for (int b = 0; b < 32; ++b) v |= (p[b] != 0 ? 1u : 0u) << b;
  bits[i] = v;
}

// ---------------------------------------------------------------- NT GEMM, 128x128 tile
// C[M,N] = A[M,K] * B[N,K]^T + bias[N]
template <int EPI>
__global__ __launch_bounds__(256) void gemm_bt(
    const unsigned short* __restrict__ A, const unsigned short* __restrict__ Bm,
    const float* __restrict__ bias, int Kdim, int Ndim,
    unsigned short* __restrict__ qb, unsigned short* __restrict__ kb,
    unsigned short* __restrict__ vtb, float* __restrict__ Cout) {
  __shared__ __align__(16) unsigned short lA[128 * 40];
  __shared__ __align__(16) unsigned short lB[128 * 40];

  int t = threadIdx.x;
  int m0 = blockIdx.y * 128, n0 = blockIdx.x * 128;
  int w = t >> 6, lane = t & 63, quad = lane >> 4, l16 = lane & 15;
  int wm = (w >> 1) * 64, wn = (w & 1) * 64;

  f32x4 acc[4][4];
#pragma unroll
  for (int i = 0; i < 4; ++i)
#pragma unroll
    for (int j = 0; j < 4; ++j) acc[i][j] = (f32x4){0.f, 0.f, 0.f, 0.f};

  int nK = Kdim >> 5;
  for (int kk = 0; kk < nK; ++kk) {
    __syncthreads();
#pragma unroll
    for (int c = 0; c < 2; ++c) {
      int id = t + c * 256;
      int row = id >> 2, c8 = (id & 3) << 3;
      *(uint4*)&lA[row * 40 + c8] =
          *(const uint4*)&A[(size_t)(m0 + row) * Kdim + (kk << 5) + c8];
      *(uint4*)&lB[row * 40 + c8] =
          *(const uint4*)&Bm[(size_t)(n0 + row) * Kdim + (kk << 5) + c8];
    }
    __syncthreads();
    short8 af[4], bfr[4];
#pragma unroll
    for (int i = 0; i < 4; ++i)
      af[i] = *(const short8*)&lA[(wm + i * 16 + l16) * 40 + quad * 8];
#pragma unroll
    for (int j = 0; j < 4; ++j)
      bfr[j] = *(const short8*)&lB[(wn + j * 16 + l16) * 40 + quad * 8];
#pragma unroll
    for (int i = 0; i < 4; ++i)
#pragma unroll
      for (int j = 0; j < 4; ++j) acc[i][j] = MFMA16(af[i], bfr[j], acc[i][j]);
  }

#pragma unroll
  for (int j = 0; j < 4; ++j) {
    int n = n0 + wn + j * 16 + l16;
    float bs = bias[n];
#pragma unroll
    for (int i = 0; i < 4; ++i) {
#pragma unroll
      for (int r = 0; r < 4; ++r) {
        int m = m0 + wm + i * 16 + quad * 4 + r;
        float v = acc[i][j][r] + bs;
        if (EPI == 0) {
          int b = m >> 11, s = m & 2047;
          int h = n / 192, rr = n % 192;
          int bh = (b << 4) + h;
          if (rr < 64)
            qb[((size_t)bh * SEQ + s) * HDIM + rr] = f2bf(v * QSCALE);
          else if (rr < 128)
            kb[((size_t)bh * SEQ + s) * HDIM + (rr - 64)] = f2bf(v);
          else
            vtb[((size_t)bh * HDIM + (rr - 128)) * SEQ + s] = f2bf(v);
        } else {
          Cout[(size_t)m * Ndim + n] = v;
        }
      }
    }
  }
}

// ---------------------------------------------------------------- flash attention
// grid: 1024 blocks (32 q-tiles of 64 rows x 32 bh), block 256 = 4 waves; wave
// owns 16 q-rows. Swapped-operand scheme: S^T = mfma(K, Q), O^T = mfma(V^T, P)
// so per-q-row softmax state lives at lane l16 (2 shfls per tile total).
// Defer-max (T13): p = exp2(s - mi) computed SPECULATIVELY with the old running
// max (off the shfl critical path); wave-uniform rescale only when max grows >5.
// K/V staged via global_load_lds, XOR-swizzled source, double-buffered.
__global__ __launch_bounds__(256, 4) void attn_kernel(
    const unsigned short* __restrict__ qbuf, const unsigned short* __restrict__ kbuf,
    const unsigned short* __restrict__ vtbuf, const unsigned int* __restrict__ mbits,
    unsigned short* __restrict__ ctx) {
  __shared__ __align__(16) unsigned short lK[2][64 * 64];
  __shared__ __align__(16) unsigned short lV[2][64 * 64];   // V^T: [d][key]
  __shared__ __align__(16) unsigned short lP[64 * 64];      // [q][key], per-wave rows

  // XCD-aware swizzle: cluster the 32 q-tiles of ~4 bh per XCD (1024 = 8*128)
  int lin = blockIdx.y * gridDim.x + blockIdx.x;
  int slin = (lin & 7) * 128 + (lin >> 3);
  int qt = slin & 31, bh = slin >> 5;
  int q0 = qt * 64;
  const unsigned short* Q = qbuf + (size_t)bh * SEQ * HDIM;
  const unsigned short* K = kbuf + (size_t)bh * SEQ * HDIM;
  const unsigned short* VT = vtbuf + (size_t)bh * HDIM * SEQ;

  int t = threadIdx.x;
  int w = t >> 6, lane = t & 63, quad = lane >> 4, l16 = lane & 15;
  int swz = (l16 & 7) << 4;          // byte-XOR swizzle for rows this lane reads

  // Q fragments in registers (scale*log2e pre-folded at projection)
  int qrow = q0 + w * 16 + l16;      // 0..2047
  short8 qf0 = *(const short8*)&Q[(size_t)qrow * HDIM + quad * 8];
  short8 qf1 = *(const short8*)&Q[(size_t)qrow * HDIM + 32 + quad * 8];

  f32x4 o[4];
#pragma unroll
  for (int jt = 0; jt < 4; ++jt) o[jt] = (f32x4){0.f, 0.f, 0.f, 0.f};
  // mi=0 is safe: logits ~ N(0, ~1.2) in log2 domain; exp2(s-0) can't overflow.
  float mi = 0.f, li = 0.f;

  // staging: round c covers rows c*32..c*32+31; wave w stages 8 rows/round.
  // global col pre-swizzled so the linear LDS dest ends up XOR-swizzled (m173).
  int scol = ((lane & 7) ^ (lane >> 3)) << 3;   // shorts; srow&7 == lane>>3
  const unsigned short* gK = K + (size_t)(w * 8 + (lane >> 3)) * HDIM + scol;
  const unsigned short* gV = VT + (size_t)(w * 8 + (lane >> 3)) * SEQ + scol;

#define STAGE_KV(buf)                                            \
  do {                                                           \
    GLDS16(gK, &lK[buf][(w * 8) * 64]);                          \
    GLDS16(gK + 32 * HDIM, &lK[buf][(32 + w * 8) * 64]);         \
    GLDS16(gV, &lV[buf][(w * 8) * 64]);                          \
    GLDS16(gV + 32 * SEQ, &lV[buf][(32 + w * 8) * 64]);          \
  } while (0)

  STAGE_KV(0);
  gK += 64 * HDIM;
  gV += 64;

  const unsigned int* mrow = mbits + (size_t)qrow * 64;
  unsigned short* lPr = &lP[(w * 16 + l16) * 64];

  for (int it = 0; it < SEQ / 64; ++it) {
    __syncthreads();   // drains vmcnt -> tile `it` staged; prev reads done
    if (it + 1 < SEQ / 64) {         // prefetch next tile into other half
      STAGE_KV((it + 1) & 1);
      gK += 64 * HDIM;
      gV += 64;
    }
    const unsigned short* cK = lK[it & 1];
    const unsigned short* cV = lV[it & 1];

    // mask: one 8B load per lane per tile (bit = key within 64-key tile)
    uint2 mw = *(const uint2*)&mrow[it * 2];

    // S^T: s[j][r] = logit[key = j*16 + quad*4 + r][qrow] (log2 domain)
    f32x4 s[4];
    __builtin_amdgcn_s_setprio(1);
#pragma unroll
    for (int j = 0; j < 4; ++j) {
      const char* kr = (const char*)&cK[(j * 16 + l16) * 64];
      short8 ka = *(const short8*)(kr + ((quad * 16) ^ swz));
      short8 kc = *(const short8*)(kr + ((64 + quad * 16) ^ swz));
      f32x4 z = (f32x4){0.f, 0.f, 0.f, 0.f};
      z = MFMA16(ka, qf0, z);
      z = MFMA16(kc, qf1, z);
      s[j] = z;
    }
    __builtin_amdgcn_s_setprio(0);

    unsigned int ma = mw.x >> (quad * 4);
    unsigned int mb = mw.y >> (quad * 4);
#pragma unroll
    for (int j = 0; j < 4; ++j) {
      unsigned int sel = (j < 2) ? ma : mb;
      int sh = (j & 1) << 4;
#pragma unroll
      for (int r = 0; r < 4; ++r)
        s[j][r] = (sel & (1u << (sh + r))) ? s[j][r] : -1e30f;
    }

    // tile max (tree, max3-fusable) — feeds only the defer check, off crit path
    float x0 = fmaxf(fmaxf(s[0][0], s[0][1]), fmaxf(s[0][2], s[0][3]));
    float x1 = fmaxf(fmaxf(s[1][0], s[1][1]), fmaxf(s[1][2], s[1][3]));
    float x2 = fmaxf(fmaxf(s[2][0], s[2][1]), fmaxf(s[2][2], s[2][3]));
    float x3 = fmaxf(fmaxf(s[3][0], s[3][1]), fmaxf(s[3][2], s[3][3]));
    float mx = fmaxf(fmaxf(x0, x1), fmaxf(x2, x3));
    mx = fmaxf(mx, __shfl_xor(mx, 16));
    mx = fmaxf(mx, __shfl_xor(mx, 32));

    // speculative P with OLD running max (no cross-lane dependency)
#pragma unroll
    for (int j = 0; j < 4; ++j)
#pragma unroll
      for (int r = 0; r < 4; ++r) s[j][r] = exp2f(s[j][r] - mi);
    float r0 = (s[0][0] + s[0][1]) + (s[0][2] + s[0][3]);
    float r1 = (s[1][0] + s[1][1]) + (s[1][2] + s[1][3]);
    float r2 = (s[2][0] + s[2][1]) + (s[2][2] + s[2][3]);
    float r3 = (s[3][0] + s[3][1]) + (s[3][2] + s[3][3]);
    float rs = (r0 + r1) + (r2 + r3);

    if (!__all(mx <= mi + 5.f)) {    // rare: running max grew too much
      float mn = fmaxf(mi, mx);
      float al = exp2f(mi - mn);
#pragma unroll
      for (int j = 0; j < 4; ++j)
#pragma unroll
        for (int r = 0; r < 4; ++r) s[j][r] *= al;
      rs *= al;
#pragma unroll
      for (int jt = 0; jt < 4; ++jt)
#pragma unroll
        for (int r = 0; r < 4; ++r) o[jt][r] *= al;
      li *= al;
      mi = mn;
    }
    rs += __shfl_xor(rs, 16);
    rs += __shfl_xor(rs, 32);
    li += rs;

    // P -> bf16 (cvt_pk) -> LDS; 4 contiguous keys per lane -> ds_write_b64
#pragma unroll
    for (int j = 0; j < 4; ++j) {
      uint2 u;
      u.x = pk2bf(s[j][0], s[j][1]);
      u.y = pk2bf(s[j][2], s[j][3]);
      *(uint2*)((char*)lPr + ((j * 32 + quad * 8) ^ swz)) = u;
    }

    // O^T += V^T P : o[jt][r] = O[d = jt*16 + quad*4 + r][qrow]
    __builtin_amdgcn_s_setprio(1);
#pragma unroll
    for (int kh = 0; kh < 2; ++kh) {
      short8 pf = *(const short8*)((const char*)lPr + ((kh * 64 + quad * 16) ^ swz));
#pragma unroll
      for (int jt = 0; jt < 4; ++jt) {
        const char* vr = (const char*)&cV[(jt * 16 + l16) * 64];
        short8 vf = *(const short8*)(vr + ((kh * 64 + quad * 16) ^ swz));
        o[jt] = MFMA16(vf, pf, o[jt]);
      }
    }
    __builtin_amdgcn_s_setprio(0);
  }

  // epilogue: 1/li is lane-local; d runs over r -> 4 contiguous bf16 per store
  float inv = 1.f / li;
  int b = bh >> 4, h = bh & 15;
  unsigned short* crow = ctx + ((size_t)(b * SEQ + qrow)) * DMODEL + h * HDIM;
#pragma unroll
  for (int jt = 0; jt < 4; ++jt) {
    uint2 u;
    u.x = pk2bf(o[jt][0] * inv, o[jt][1] * inv);
    u.y = pk2bf(o[jt][2] * inv, o[jt][3] * inv);
    *(uint2*)&crow[jt * 16 + quad * 4] = u;
  }
}

// ---------------------------------------------------------------- launch
extern "C" void kernel_launch(void* const* d_in, const int* in_sizes, int n_in,
                              void* d_out, int out_size, void* d_ws, size_t ws_size,
                              hipStream_t stream) {
  const float* x = (const float*)d_in[0];
  const int* mask = (const int*)d_in[1];
  const float* w_qkv = (const float*)d_in[2];
  const float* b_qkv = (const float*)d_in[3];
  const float* w_o = (const float*)d_in[4];
  const float* b_o = (const float*)d_in[5];
  float* out = (float*)d_out;

  char* ws = (char*)d_ws;
  unsigned short* xb = (unsigned short*)(ws);                       // 8 MB
  unsigned short* wqkvb = (unsigned short*)(ws + (8ull << 20));     // 6 MB
  unsigned short* wob = (unsigned short*)(ws + (14ull << 20));      // 2 MB
  unsigned short* qb = (unsigned short*)(ws + (16ull << 20));       // 8 MB
  unsigned short* kb = (unsigned short*)(ws + (24ull << 20));       // 8 MB
  unsigned short* vtb = (unsigned short*)(ws + (32ull << 20));      // 8 MB
  unsigned short* ctx = (unsigned short*)(ws + (40ull << 20));      // 8 MB
  unsigned int* mbits = (unsigned int*)(ws + (48ull << 20));        // 512 KB

  cvt_kernel<<<4096, 256, 0, stream>>>(x, xb, (MROWS * DMODEL) / 4);
  cvt_kernel<<<3072, 256, 0, stream>>>(w_qkv, wqkvb, (N_QKV * DMODEL) / 4);
  cvt_kernel<<<1024, 256, 0, stream>>>(w_o, wob, (DMODEL * DMODEL) / 4);
  mask_to_bits<<<512, 256, 0, stream>>>(mask, mbits);

  gemm_bt<0><<<dim3(N_QKV / 128, MROWS / 128), 256, 0, stream>>>(
      xb, wqkvb, b_qkv, DMODEL, N_QKV, qb, kb, vtb, nullptr);

  attn_kernel<<<dim3(SEQ / 64, BATCH * NHEADS), 256, 0, stream>>>(
      qb, kb, vtb, mbits, ctx);

  gemm_bt<1><<<dim3(DMODEL / 128, MROWS / 128), 256, 0, stream>>>(
      ctx, wob, b_o, DMODEL, DMODEL, nullptr, nullptr, nullptr, out);
}